// Round 4
// baseline (765.937 us; speedup 1.0000x reference)
//
#include <hip/hip_runtime.h>
#include <math.h>

#define N_TOK 2048
#define DIM   1024
#define NEXP  8
#define HID   4096
#define TOTPAIR (2 * N_TOK)

#define BM 128
#define BN 128
#define BK 64
#define KSPLIT2 4

typedef __bf16 bf16x8 __attribute__((ext_vector_type(8)));
typedef __bf16 bf16x4 __attribute__((ext_vector_type(4)));
typedef float  f32x4  __attribute__((ext_vector_type(4)));

__device__ __forceinline__ float gelu_tanh(float v) {
    float a = 0.7978845608028654f * (v + 0.044715f * v * v * v);
    a = fminf(fmaxf(a, -15.f), 15.f);
    float t = __expf(-2.f * a);
    return 0.5f * v * (1.f + (1.f - t) / (1.f + t));
}

// Stage 16B/lane: global (per-lane addr) -> LDS (wave-uniform base; HW scatters lane i -> base+16i).
__device__ __forceinline__ void stage16(const __bf16* g, __bf16* lds_base, int lane) {
#if defined(__has_builtin) && __has_builtin(__builtin_amdgcn_global_load_lds)
    __builtin_amdgcn_global_load_lds((const __attribute__((address_space(1))) void*)g,
                                     (__attribute__((address_space(3))) void*)lds_base,
                                     16, 0, 0);
#else
    *(bf16x8*)((char*)lds_base + (size_t)lane * 16) = *(const bf16x8*)g;
#endif
}

__device__ __forceinline__ int expert_prefix(const int* cnt, int e) {
    int s = 0;
    for (int i = 0; i < NEXP; i++) s += (i < e) ? cnt[i] : 0;
    return s;
}

// ---------------- router ----------------
__global__ void router_kernel(const float* __restrict__ x, const float* __restrict__ Wr,
                              const float* __restrict__ br,
                              float* __restrict__ probs, float* __restrict__ lsq,
                              int* __restrict__ cnt, int* __restrict__ tok,
                              float* __restrict__ wl) {
    const int t = blockIdx.x;
    const int lane = threadIdx.x;
    const float* xr = x + (size_t)t * DIM;
    float acc[NEXP];
#pragma unroll
    for (int e = 0; e < NEXP; e++) acc[e] = 0.f;
    for (int d = lane; d < DIM; d += 64) {
        float xv = xr[d];
        const float* wr = Wr + (size_t)d * NEXP;
#pragma unroll
        for (int e = 0; e < NEXP; e++) acc[e] = fmaf(xv, wr[e], acc[e]);
    }
#pragma unroll
    for (int off = 32; off >= 1; off >>= 1) {
#pragma unroll
        for (int e = 0; e < NEXP; e++) acc[e] += __shfl_xor(acc[e], off, 64);
    }
    if (lane == 0) {
        float lg[NEXP], mx = -1e30f;
#pragma unroll
        for (int e = 0; e < NEXP; e++) { lg[e] = acc[e] + br[e]; mx = fmaxf(mx, lg[e]); }
        float se = 0.f, p[NEXP];
#pragma unroll
        for (int e = 0; e < NEXP; e++) { p[e] = expf(lg[e] - mx); se += p[e]; }
        float inv = 1.f / se;
        float lse = mx + logf(se);
        lsq[t] = lse * lse;
#pragma unroll
        for (int e = 0; e < NEXP; e++) probs[t * NEXP + e] = p[e] * inv;
        int i0 = 0;
#pragma unroll
        for (int e = 1; e < NEXP; e++) if (p[e] > p[i0]) i0 = e;
        int i1 = (i0 == 0) ? 1 : 0;
#pragma unroll
        for (int e = 0; e < NEXP; e++) if (e != i0 && p[e] > p[i1]) i1 = e;
        float p0 = p[i0] * inv, p1 = p[i1] * inv;
        float rn = 1.f / (p0 + p1 + 1e-12f);
        int pos0 = atomicAdd(&cnt[i0], 1);
        tok[i0 * N_TOK + pos0] = t;
        wl[i0 * N_TOK + pos0] = p0 * rn;
        int pos1 = atomicAdd(&cnt[i1], 1);
        tok[i1 * N_TOK + pos1] = t;
        wl[i1 * N_TOK + pos1] = p1 * rn;
    }
}

// ---------------- conversions ----------------
__global__ void conv_x_kernel(const float* __restrict__ x, __bf16* __restrict__ xb) {
    int idx = blockIdx.x * 256 + threadIdx.x;
    float4 v = ((const float4*)x)[idx];
    bf16x4 o;
    o.x = (__bf16)v.x; o.y = (__bf16)v.y; o.z = (__bf16)v.z; o.w = (__bf16)v.w;
    ((bf16x4*)xb)[idx] = o;
}

// in: [R][C] fp32 per expert (blockIdx.z), out: [C][R] bf16. 64x64 tiles.
__global__ __launch_bounds__(256) void transpose_conv_kernel(
    const float* __restrict__ in, __bf16* __restrict__ out, int R, int C) {
    __shared__ __bf16 tile[64][68];
    const int t = threadIdx.x;
    const size_t eoff = (size_t)blockIdx.z * (size_t)R * (size_t)C;
    const int rb = blockIdx.y * 64, cb = blockIdx.x * 64;
    const int r = t >> 4, c4 = (t & 15) * 4;
#pragma unroll
    for (int i = 0; i < 4; i++) {
        int row = r + i * 16;
        float4 v = *(const float4*)(in + eoff + (size_t)(rb + row) * C + cb + c4);
        bf16x4 o;
        o.x = (__bf16)v.x; o.y = (__bf16)v.y; o.z = (__bf16)v.z; o.w = (__bf16)v.w;
        *(bf16x4*)&tile[row][c4] = o;
    }
    __syncthreads();
    const int c = t >> 2, ch0 = t & 3;
#pragma unroll
    for (int i = 0; i < 2; i++) {
        int ch = ch0 + i * 4;
        bf16x8 o;
#pragma unroll
        for (int j = 0; j < 8; j++) o[j] = tile[ch * 8 + j][c];
        *(bf16x8*)(out + eoff + (size_t)(cb + c) * R + rb + ch * 8) = o;
    }
}

// ---------------- GEMM1: h = gelu(gather(x) @ W1e + b1) ----------------
// LDS tiles [row][BK=64], 8-chunk XOR swizzle: chunk of row r lives at slot chunk^(r&7).
__global__ __launch_bounds__(256, 4) void gemm1_kernel(
    const __bf16* __restrict__ xb, const __bf16* __restrict__ W1T,
    const float* __restrict__ b1,
    const int* __restrict__ cnt,
    const int* __restrict__ tok, __bf16* __restrict__ h) {
    const int e = blockIdx.z;
    const int ce = cnt[e];
    const int mstart = blockIdx.y * BM;
    if (mstart >= ce) return;
    const int n0 = blockIdx.x * BN;
    const int offe = expert_prefix(cnt, e);

    __shared__ __bf16 smem[BM * BK * 2];   // As | Bs ; reused as 128x128 C-buffer
    __shared__ int toksh[BM];
    __bf16* As = smem;
    __bf16* Bs = smem + BM * BK;

    const int tid = threadIdx.x;
    if (tid < BM) {
        int idx = mstart + tid;
        toksh[tid] = (idx < ce) ? tok[e * N_TOK + idx] : 0;
    }
    __syncthreads();

    const int lane = tid & 63;
    const int wid  = tid >> 6;
    const int row0 = (wid >> 1) * 64;
    const int col0 = (wid & 1) * 64;
    const int quad = lane >> 4;
    const int lcol = lane & 15;

    // staging: wave stages rows [wid*32, wid*32+32) of A and B, 4 calls of 8 rows each
    const int wbase = wid * 32;
    const int srow  = lane >> 3;              // 0..7 within call
    const int gch   = (lane & 7) ^ srow;      // swizzled global chunk for this lane

    const __bf16* __restrict__ W1e = W1T + (size_t)e * HID * DIM;
    const __bf16* pA[4]; const __bf16* pB[4];
    __bf16* lA[4]; __bf16* lB[4];
#pragma unroll
    for (int c = 0; c < 4; c++) {
        int r = wbase + c * 8 + srow;
        pA[c] = xb + (size_t)toksh[r] * DIM + gch * 8;
        pB[c] = W1e + (size_t)(n0 + r) * DIM + gch * 8;
        lA[c] = As + (wbase + c * 8) * BK;
        lB[c] = Bs + (wbase + c * 8) * BK;
    }

    f32x4 acc[4][4];
#pragma unroll
    for (int i = 0; i < 4; i++)
#pragma unroll
        for (int j = 0; j < 4; j++) acc[i][j] = (f32x4){0.f, 0.f, 0.f, 0.f};

    for (int k0 = 0; k0 < DIM; k0 += BK) {
#pragma unroll
        for (int c = 0; c < 4; c++) {
            stage16(pA[c] + k0, lA[c], lane);
            stage16(pB[c] + k0, lB[c], lane);
        }
        __syncthreads();
#pragma unroll
        for (int kw = 0; kw < 2; kw++) {
            const int soff = (((kw * 4 + quad) ^ (lcol & 7)) << 3);
            bf16x8 af[4], bfr[4];
#pragma unroll
            for (int i = 0; i < 4; i++) af[i]  = *(const bf16x8*)&As[(row0 + i * 16 + lcol) * BK + soff];
#pragma unroll
            for (int j = 0; j < 4; j++) bfr[j] = *(const bf16x8*)&Bs[(col0 + j * 16 + lcol) * BK + soff];
#pragma unroll
            for (int i = 0; i < 4; i++)
#pragma unroll
                for (int j = 0; j < 4; j++)
                    acc[i][j] = __builtin_amdgcn_mfma_f32_16x16x32_bf16(af[i], bfr[j], acc[i][j], 0, 0, 0);
        }
        __syncthreads();
    }

    // epilogue: bias+gelu -> swizzled 128x128 bf16 C-buffer -> coalesced bf16x8 stores
    const float* __restrict__ b1e = b1 + (size_t)e * HID;
    float bj[4];
#pragma unroll
    for (int j = 0; j < 4; j++) bj[j] = b1e[n0 + col0 + j * 16 + lcol];
#pragma unroll
    for (int i = 0; i < 4; i++)
#pragma unroll
        for (int reg = 0; reg < 4; reg++) {
            int row = row0 + i * 16 + quad * 4 + reg;
#pragma unroll
            for (int j = 0; j < 4; j++) {
                int col = col0 + j * 16 + lcol;
                int slot = (col >> 3) ^ (row & 15);
                smem[row * 128 + slot * 8 + (col & 7)] =
                    (__bf16)gelu_tanh(acc[i][j][reg] + bj[j]);
            }
        }
    __syncthreads();
    {
        int row = tid >> 1, half = tid & 1;
        int pos = mstart + row;
        if (pos < ce) {
            __bf16* hp = h + (size_t)(offe + pos) * HID + n0 + half * 64;
#pragma unroll
            for (int j = 0; j < 8; j++) {
                int chunk = half * 8 + j;
                int slot = chunk ^ (row & 15);
                *(bf16x8*)(hp + j * 8) = *(const bf16x8*)&smem[row * 128 + slot * 8];
            }
        }
    }
}

// ---------------- GEMM2: out[tok] += w * (h @ W2e + b2), split-K ----------------
__global__ __launch_bounds__(256, 4) void gemm2_kernel(
    const __bf16* __restrict__ h, const __bf16* __restrict__ W2T,
    const float* __restrict__ b2,
    const int* __restrict__ cnt,
    const int* __restrict__ tok, const float* __restrict__ wl,
    float* __restrict__ out) {
    const int e = blockIdx.z >> 2;
    const int split = blockIdx.z & 3;
    const int ce = cnt[e];
    const int mstart = blockIdx.y * BM;
    if (mstart >= ce) return;
    const int n0 = blockIdx.x * BN;
    const int ks = split * (HID / KSPLIT2);
    const int offe = expert_prefix(cnt, e);

    __shared__ __bf16 smem[BM * BK * 2];
    __shared__ int   toksh[BM];
    __shared__ float wsh[BM];
    __bf16* As = smem;
    __bf16* Bs = smem + BM * BK;

    const int tid = threadIdx.x;
    if (tid < BM) {
        int idx = mstart + tid;
        toksh[tid] = (idx < ce) ? tok[e * N_TOK + idx] : 0;
        wsh[tid]   = (idx < ce) ? wl[e * N_TOK + idx] : 0.f;
    }
    __syncthreads();

    const int lane = tid & 63;
    const int wid  = tid >> 6;
    const int row0 = (wid >> 1) * 64;
    const int col0 = (wid & 1) * 64;
    const int quad = lane >> 4;
    const int lcol = lane & 15;

    const int wbase = wid * 32;
    const int srow  = lane >> 3;
    const int gch   = (lane & 7) ^ srow;

    const __bf16* __restrict__ W2e = W2T + (size_t)e * DIM * HID;
    const __bf16* pA[4]; const __bf16* pB[4];
    __bf16* lA[4]; __bf16* lB[4];
#pragma unroll
    for (int c = 0; c < 4; c++) {
        int r = wbase + c * 8 + srow;
        int hr = offe + mstart + r; if (hr >= TOTPAIR) hr = TOTPAIR - 1;
        pA[c] = h + (size_t)hr * HID + ks + gch * 8;
        pB[c] = W2e + (size_t)(n0 + r) * HID + ks + gch * 8;
        lA[c] = As + (wbase + c * 8) * BK;
        lB[c] = Bs + (wbase + c * 8) * BK;
    }

    f32x4 acc[4][4];
#pragma unroll
    for (int i = 0; i < 4; i++)
#pragma unroll
        for (int j = 0; j < 4; j++) acc[i][j] = (f32x4){0.f, 0.f, 0.f, 0.f};

    for (int k0 = 0; k0 < HID / KSPLIT2; k0 += BK) {
#pragma unroll
        for (int c = 0; c < 4; c++) {
            stage16(pA[c] + k0, lA[c], lane);
            stage16(pB[c] + k0, lB[c], lane);
        }
        __syncthreads();
#pragma unroll
        for (int kw = 0; kw < 2; kw++) {
            const int soff = (((kw * 4 + quad) ^ (lcol & 7)) << 3);
            bf16x8 af[4], bfr[4];
#pragma unroll
            for (int i = 0; i < 4; i++) af[i]  = *(const bf16x8*)&As[(row0 + i * 16 + lcol) * BK + soff];
#pragma unroll
            for (int j = 0; j < 4; j++) bfr[j] = *(const bf16x8*)&Bs[(col0 + j * 16 + lcol) * BK + soff];
#pragma unroll
            for (int i = 0; i < 4; i++)
#pragma unroll
                for (int j = 0; j < 4; j++)
                    acc[i][j] = __builtin_amdgcn_mfma_f32_16x16x32_bf16(af[i], bfr[j], acc[i][j], 0, 0, 0);
        }
        __syncthreads();
    }

    const float* __restrict__ b2e = b2 + (size_t)e * DIM;
    const bool addBias = (split == 0);
#pragma unroll
    for (int i = 0; i < 4; i++) {
#pragma unroll
        for (int reg = 0; reg < 4; reg++) {
            int lrow = row0 + i * 16 + quad * 4 + reg;
            int pos = mstart + lrow;
            if (pos >= ce) continue;
            int tokm = toksh[lrow];
            float w = wsh[lrow];
#pragma unroll
            for (int j = 0; j < 4; j++) {
                int gcol = n0 + col0 + j * 16 + lcol;
                float v = acc[i][j][reg] + (addBias ? b2e[gcol] : 0.f);
                atomicAdd(&out[(size_t)tokm * DIM + gcol], w * v);
            }
        }
    }
}

// ---------------- fp32 fallback FFN ----------------
__global__ __launch_bounds__(256, 2) void ffn_fallback_kernel(
    const float* __restrict__ x,
    const float* __restrict__ W1, const float* __restrict__ b1,
    const float* __restrict__ W2, const float* __restrict__ b2,
    const int* __restrict__ cnt, const int* __restrict__ tok,
    const float* __restrict__ wl, float* __restrict__ out) {
    const int e = blockIdx.y;
    const int ce = cnt[e];
    const int start = blockIdx.x * 16;
    if (start >= ce) return;
    __shared__ float hs[16][128];
    __shared__ int toks[16];
    __shared__ float wgt[16];
    const int tid = threadIdx.x;
    if (tid < 16) {
        int idx = start + tid;
        if (idx < ce) { toks[tid] = tok[e * N_TOK + idx]; wgt[tid] = wl[e * N_TOK + idx]; }
        else          { toks[tid] = -1;                   wgt[tid] = 0.f; }
    }
    __syncthreads();
    const float* __restrict__ W1e = W1 + (size_t)e * DIM * HID;
    const float* __restrict__ W2e = W2 + (size_t)e * HID * DIM;
    const int am  = tid >> 4;
    const int aj0 = (tid & 15) * 8;
    const int at  = toks[am];
    const float* __restrict__ xrow = x + (size_t)(at < 0 ? 0 : at) * DIM;
    const int n0 = tid * 4;
    float acc[16][4];
#pragma unroll
    for (int m = 0; m < 16; m++)
#pragma unroll
        for (int i = 0; i < 4; i++) acc[m][i] = 0.f;
    for (int c = 0; c < HID; c += 128) {
        float ha[8];
#pragma unroll
        for (int r = 0; r < 8; r++) ha[r] = 0.f;
        const float* wp = W1e + c + aj0;
        for (int d = 0; d < DIM; d += 4) {
            float4 xv = *(const float4*)(xrow + d);
#pragma unroll
            for (int k = 0; k < 4; k++) {
                const float* wr = wp + (size_t)(d + k) * HID;
                float4 wa = *(const float4*)(wr);
                float4 wb = *(const float4*)(wr + 4);
                float xk = (k == 0) ? xv.x : (k == 1) ? xv.y : (k == 2) ? xv.z : xv.w;
                ha[0] = fmaf(xk, wa.x, ha[0]); ha[1] = fmaf(xk, wa.y, ha[1]);
                ha[2] = fmaf(xk, wa.z, ha[2]); ha[3] = fmaf(xk, wa.w, ha[3]);
                ha[4] = fmaf(xk, wb.x, ha[4]); ha[5] = fmaf(xk, wb.y, ha[5]);
                ha[6] = fmaf(xk, wb.z, ha[6]); ha[7] = fmaf(xk, wb.w, ha[7]);
            }
        }
        __syncthreads();
#pragma unroll
        for (int r = 0; r < 8; r++) {
            float v = ha[r] + b1[e * HID + c + aj0 + r];
            hs[am][aj0 + r] = gelu_tanh(v);
        }
        __syncthreads();
        for (int jj = 0; jj < 128; jj++) {
            float4 wv = *(const float4*)(W2e + (size_t)(c + jj) * DIM + n0);
#pragma unroll
            for (int m = 0; m < 16; m++) {
                float hv = hs[m][jj];
                acc[m][0] = fmaf(hv, wv.x, acc[m][0]); acc[m][1] = fmaf(hv, wv.y, acc[m][1]);
                acc[m][2] = fmaf(hv, wv.z, acc[m][2]); acc[m][3] = fmaf(hv, wv.w, acc[m][3]);
            }
        }
    }
    const float* bp = b2 + e * DIM + n0;
    float b0 = bp[0], b1v = bp[1], b2v = bp[2], b3 = bp[3];
#pragma unroll 1
    for (int m = 0; m < 16; m++) {
        int t = toks[m];
        if (t < 0) continue;
        float w = wgt[m];
        float* op = out + (size_t)t * DIM + n0;
        atomicAdd(op + 0, w * (acc[m][0] + b0));
        atomicAdd(op + 1, w * (acc[m][1] + b1v));
        atomicAdd(op + 2, w * (acc[m][2] + b2v));
        atomicAdd(op + 3, w * (acc[m][3] + b3));
    }
}

// ---------------- finalize ----------------
__global__ void finalize_kernel(const float* __restrict__ probs, const float* __restrict__ lsq,
                                const int* __restrict__ cnt, float* __restrict__ scal) {
    __shared__ float part[256][9];
    const int tid = threadIdx.x;
    float z = 0.f;
    float im[NEXP];
#pragma unroll
    for (int e = 0; e < NEXP; e++) im[e] = 0.f;
    for (int t = tid; t < N_TOK; t += 256) {
        z += lsq[t];
#pragma unroll
        for (int e = 0; e < NEXP; e++) im[e] += probs[t * NEXP + e];
    }
    part[tid][0] = z;
#pragma unroll
    for (int e = 0; e < NEXP; e++) part[tid][1 + e] = im[e];
    __syncthreads();
    if (tid == 0) {
        float zs = 0.f, ims[NEXP];
        for (int e = 0; e < NEXP; e++) ims[e] = 0.f;
        for (int i = 0; i < 256; i++) {
            zs += part[i][0];
            for (int e = 0; e < NEXP; e++) ims[e] += part[i][1 + e];
        }
        float nInv = 1.0f / (float)N_TOK;
        float aux = 0.f;
        for (int e = 0; e < NEXP; e++) aux += (ims[e] * nInv) * ((float)cnt[e] * nInv);
        scal[0] = zs * nInv;
        scal[1] = (float)NEXP * aux;
    }
}

extern "C" void kernel_launch(void* const* d_in, const int* in_sizes, int n_in,
                              void* d_out, int out_size, void* d_ws, size_t ws_size,
                              hipStream_t stream) {
    const float* x  = (const float*)d_in[0];
    const float* Wr = (const float*)d_in[1];
    const float* br = (const float*)d_in[2];
    const float* W1 = (const float*)d_in[3];
    const float* b1 = (const float*)d_in[4];
    const float* W2 = (const float*)d_in[5];
    const float* b2 = (const float*)d_in[6];
    float* out = (float*)d_out;

    char* base = (char*)d_ws;
    int*   cnt   = (int*)(base);
    int*   tokp  = (int*)(base + 64);
    float* wlp   = (float*)(base + 64 + 65536);
    float* probs = (float*)(base + 64 + 2 * 65536);
    float* lsq   = (float*)(base + 64 + 3 * 65536);
    const size_t SMALL_END = 64 + 3 * 65536 + 8192;
    __bf16* xb   = (__bf16*)(base + SMALL_END);
    __bf16* W1T  = (__bf16*)(base + SMALL_END + 4194304ull);
    __bf16* W2T  = (__bf16*)(base + SMALL_END + 4194304ull + 67108864ull);
    __bf16* hbuf = (__bf16*)(base + SMALL_END + 4194304ull + 2ull * 67108864ull);
    const size_t REQ = SMALL_END + 4194304ull + 2ull * 67108864ull + 33554432ull;

    hipMemsetAsync(base, 0, 64, stream);
    hipMemsetAsync(d_out, 0, (size_t)out_size * sizeof(float), stream);

    router_kernel<<<N_TOK, 64, 0, stream>>>(x, Wr, br, probs, lsq, cnt, tokp, wlp);

    if (ws_size >= REQ) {
        conv_x_kernel<<<(N_TOK * DIM / 4) / 256, 256, 0, stream>>>(x, xb);
        transpose_conv_kernel<<<dim3(HID / 64, DIM / 64, NEXP), 256, 0, stream>>>(W1, W1T, DIM, HID);
        transpose_conv_kernel<<<dim3(DIM / 64, HID / 64, NEXP), 256, 0, stream>>>(W2, W2T, HID, DIM);
        gemm1_kernel<<<dim3(HID / BN, N_TOK / BM, NEXP), 256, 0, stream>>>(
            xb, W1T, b1, cnt, tokp, hbuf);
        gemm2_kernel<<<dim3(DIM / BN, N_TOK / BM, NEXP * KSPLIT2), 256, 0, stream>>>(
            hbuf, W2T, b2, cnt, tokp, wlp, out);
    } else {
        ffn_fallback_kernel<<<dim3(128, NEXP), 256, 0, stream>>>(
            x, W1, b1, W2, b2, cnt, tokp, wlp, out);
    }

    finalize_kernel<<<1, 256, 0, stream>>>(probs, lsq, cnt, out + (size_t)N_TOK * DIM);
}

// Round 5
// 633.791 us; speedup vs baseline: 1.2085x; 1.2085x over previous
//
#include <hip/hip_runtime.h>
#include <math.h>

#define N_TOK 2048
#define DIM   1024
#define NEXP  8
#define HID   4096
#define TOTPAIR (2 * N_TOK)

#define BM 128
#define BN 128
#define BK 32
#define KSPLIT2 4

typedef __bf16 bf16x8 __attribute__((ext_vector_type(8)));
typedef __bf16 bf16x4 __attribute__((ext_vector_type(4)));
typedef float  f32x4  __attribute__((ext_vector_type(4)));

__device__ __forceinline__ float gelu_tanh(float v) {
    float a = 0.7978845608028654f * (v + 0.044715f * v * v * v);
    a = fminf(fmaxf(a, -15.f), 15.f);
    float t = __expf(-2.f * a);
    return 0.5f * v * (1.f + (1.f - t) / (1.f + t));
}

// Stage 16B/lane: global (per-lane addr) -> LDS (wave-uniform base; HW scatters lane i -> base+16i).
__device__ __forceinline__ void stage16(const __bf16* g, __bf16* lds_base, int lane) {
#if defined(__has_builtin) && __has_builtin(__builtin_amdgcn_global_load_lds)
    __builtin_amdgcn_global_load_lds((const __attribute__((address_space(1))) void*)g,
                                     (__attribute__((address_space(3))) void*)lds_base,
                                     16, 0, 0);
#else
    *(bf16x8*)((char*)lds_base + (size_t)lane * 16) = *(const bf16x8*)g;
#endif
}

__device__ __forceinline__ int expert_prefix(const int* cnt, int e) {
    int s = 0;
    for (int i = 0; i < NEXP; i++) s += (i < e) ? cnt[i] : 0;
    return s;
}

// ---------------- router body (one wave per token) ----------------
__device__ __forceinline__ void router_body(
    int t, int lane,
    const float* __restrict__ x, const float* __restrict__ Wr, const float* __restrict__ br,
    float* __restrict__ probs, float* __restrict__ lsq,
    int* __restrict__ cnt, int* __restrict__ tok, float* __restrict__ wl) {
    const float* xr = x + (size_t)t * DIM;
    float acc[NEXP];
#pragma unroll
    for (int e = 0; e < NEXP; e++) acc[e] = 0.f;
    for (int d = lane; d < DIM; d += 64) {
        float xv = xr[d];
        const float* wr = Wr + (size_t)d * NEXP;
#pragma unroll
        for (int e = 0; e < NEXP; e++) acc[e] = fmaf(xv, wr[e], acc[e]);
    }
#pragma unroll
    for (int off = 32; off >= 1; off >>= 1) {
#pragma unroll
        for (int e = 0; e < NEXP; e++) acc[e] += __shfl_xor(acc[e], off, 64);
    }
    if (lane == 0) {
        float lg[NEXP], mx = -1e30f;
#pragma unroll
        for (int e = 0; e < NEXP; e++) { lg[e] = acc[e] + br[e]; mx = fmaxf(mx, lg[e]); }
        float se = 0.f, p[NEXP];
#pragma unroll
        for (int e = 0; e < NEXP; e++) { p[e] = expf(lg[e] - mx); se += p[e]; }
        float inv = 1.f / se;
        float lse = mx + logf(se);
        lsq[t] = lse * lse;
#pragma unroll
        for (int e = 0; e < NEXP; e++) probs[t * NEXP + e] = p[e] * inv;
        int i0 = 0;
#pragma unroll
        for (int e = 1; e < NEXP; e++) if (p[e] > p[i0]) i0 = e;
        int i1 = (i0 == 0) ? 1 : 0;
#pragma unroll
        for (int e = 0; e < NEXP; e++) if (e != i0 && p[e] > p[i1]) i1 = e;
        float p0 = p[i0] * inv, p1 = p[i1] * inv;
        float rn = 1.f / (p0 + p1 + 1e-12f);
        int pos0 = atomicAdd(&cnt[i0], 1);
        tok[i0 * N_TOK + pos0] = t;
        wl[i0 * N_TOK + pos0] = p0 * rn;
        int pos1 = atomicAdd(&cnt[i1], 1);
        tok[i1 * N_TOK + pos1] = t;
        wl[i1 * N_TOK + pos1] = p1 * rn;
    }
}

// ---------------- standalone router (fallback path) ----------------
__global__ void router_kernel(const float* __restrict__ x, const float* __restrict__ Wr,
                              const float* __restrict__ br,
                              float* __restrict__ probs, float* __restrict__ lsq,
                              int* __restrict__ cnt, int* __restrict__ tok,
                              float* __restrict__ wl) {
    router_body(blockIdx.x, threadIdx.x, x, Wr, br, probs, lsq, cnt, tok, wl);
}

// ---------------- fused prep: router | x->bf16 | W1 transpose | W2 transpose ----------------
#define PREP_ROUTER 512
#define PREP_CONV   2048
#define PREP_T1     8192
#define PREP_T2     8192

__global__ __launch_bounds__(256) void prep_kernel(
    const float* __restrict__ x, const float* __restrict__ Wr, const float* __restrict__ br,
    float* __restrict__ probs, float* __restrict__ lsq,
    int* __restrict__ cnt, int* __restrict__ tok, float* __restrict__ wl,
    __bf16* __restrict__ xb,
    const float* __restrict__ W1, __bf16* __restrict__ W1T,
    const float* __restrict__ W2, __bf16* __restrict__ W2T) {
    __shared__ __bf16 tile[64][68];
    const int b = blockIdx.x;
    const int tid = threadIdx.x;

    if (b < PREP_ROUTER) {
        int t = b * 4 + (tid >> 6);
        router_body(t, tid & 63, x, Wr, br, probs, lsq, cnt, tok, wl);
        return;
    }
    if (b < PREP_ROUTER + PREP_CONV) {
        int idx = (b - PREP_ROUTER) * 256 + tid;
        float4 v = ((const float4*)x)[idx];
        bf16x4 o;
        o.x = (__bf16)v.x; o.y = (__bf16)v.y; o.z = (__bf16)v.z; o.w = (__bf16)v.w;
        ((bf16x4*)xb)[idx] = o;
        return;
    }
    // transpose roles: in [R][C] fp32 -> out [C][R] bf16 per expert
    const float* in; __bf16* out; int R, C, bx, by, bz;
    if (b < PREP_ROUTER + PREP_CONV + PREP_T1) {
        int bb = b - (PREP_ROUTER + PREP_CONV);
        in = W1; out = W1T; R = DIM; C = HID;
        bx = bb & 63; by = (bb >> 6) & 15; bz = bb >> 10;   // 64 x 16 x 8
    } else {
        int bb = b - (PREP_ROUTER + PREP_CONV + PREP_T1);
        in = W2; out = W2T; R = HID; C = DIM;
        bx = bb & 15; by = (bb >> 4) & 63; bz = bb >> 10;   // 16 x 64 x 8
    }
    const size_t eoff = (size_t)bz * (size_t)R * (size_t)C;
    const int rb = by * 64, cb = bx * 64;
    const int r = tid >> 4, c4 = (tid & 15) * 4;
#pragma unroll
    for (int i = 0; i < 4; i++) {
        int row = r + i * 16;
        float4 v = *(const float4*)(in + eoff + (size_t)(rb + row) * C + cb + c4);
        bf16x4 o;
        o.x = (__bf16)v.x; o.y = (__bf16)v.y; o.z = (__bf16)v.z; o.w = (__bf16)v.w;
        *(bf16x4*)&tile[row][c4] = o;
    }
    __syncthreads();
    const int c = tid >> 2, ch0 = tid & 3;
#pragma unroll
    for (int i = 0; i < 2; i++) {
        int ch = ch0 + i * 4;
        bf16x8 o;
#pragma unroll
        for (int j = 0; j < 8; j++) o[j] = tile[ch * 8 + j][c];
        *(bf16x8*)(out + eoff + (size_t)(cb + c) * R + rb + ch * 8) = o;
    }
}

// ---------------- GEMM1: h = gelu(gather(x) @ W1e + b1), BK=32, XCD-grouped ----------------
// 1D grid 4096: L = xcd + 8*(n + 32*grp), key = grp*8+xcd = e*16+m.
// All 32 n-blocks of one (e,m) share an XCD -> x-tile L2 reuse; W1 via L3.
__global__ __launch_bounds__(256, 4) void gemm1_kernel(
    const __bf16* __restrict__ xb, const __bf16* __restrict__ W1T,
    const float* __restrict__ b1,
    const int* __restrict__ cnt,
    const int* __restrict__ tok, __bf16* __restrict__ h) {
    const int L = blockIdx.x;
    const int xcd = L & 7;
    const int r1 = L >> 3;
    const int n = r1 & 31;
    const int key = (r1 >> 5) * 8 + xcd;
    const int e = key >> 4;
    const int m = key & 15;
    const int ce = cnt[e];
    const int mstart = m * BM;
    if (mstart >= ce) return;
    const int n0 = n * BN;
    const int offe = expert_prefix(cnt, e);

    __shared__ __bf16 smem[BM * 128];       // 32 KB; As|Bs in first 16 KB, full as C-buffer
    __shared__ int toksh[BM];
    __bf16* As = smem;
    __bf16* Bs = smem + BM * BK;

    const int tid = threadIdx.x;
    if (tid < BM) {
        int idx = mstart + tid;
        toksh[tid] = (idx < ce) ? tok[e * N_TOK + idx] : 0;
    }
    __syncthreads();

    const int lane = tid & 63;
    const int wid  = tid >> 6;
    const int row0 = (wid >> 1) * 64;
    const int col0 = (wid & 1) * 64;
    const int quad = lane >> 4;
    const int lcol = lane & 15;

    const int sub = lane >> 2;
    const int gk  = (((lane & 3) ^ (sub & 3)) << 3);
    const int ra0 = wid * 32 + sub;
    const int ra1 = ra0 + 16;

    const __bf16* __restrict__ W1e = W1T + (size_t)e * HID * DIM;
    const __bf16* pA0 = xb + (size_t)toksh[ra0] * DIM + gk;
    const __bf16* pA1 = xb + (size_t)toksh[ra1] * DIM + gk;
    const __bf16* pB0 = W1e + (size_t)(n0 + ra0) * DIM + gk;
    const __bf16* pB1 = W1e + (size_t)(n0 + ra1) * DIM + gk;
    __bf16* lA0 = &As[(wid * 2 + 0) * 512];
    __bf16* lA1 = &As[(wid * 2 + 1) * 512];
    __bf16* lB0 = &Bs[(wid * 2 + 0) * 512];
    __bf16* lB1 = &Bs[(wid * 2 + 1) * 512];

    const int swz = (quad ^ (lcol & 3)) << 3;
    const __bf16* aF = &As[(row0 + lcol) * BK + swz];
    const __bf16* bF = &Bs[(col0 + lcol) * BK + swz];

    f32x4 acc[4][4];
#pragma unroll
    for (int i = 0; i < 4; i++)
#pragma unroll
        for (int j = 0; j < 4; j++) acc[i][j] = (f32x4){0.f, 0.f, 0.f, 0.f};

    for (int k0 = 0; k0 < DIM; k0 += BK) {
        stage16(pA0 + k0, lA0, lane);
        stage16(pA1 + k0, lA1, lane);
        stage16(pB0 + k0, lB0, lane);
        stage16(pB1 + k0, lB1, lane);
        __syncthreads();
        bf16x8 af[4], bfr[4];
#pragma unroll
        for (int i = 0; i < 4; i++) af[i]  = *(const bf16x8*)(aF + i * 16 * BK);
#pragma unroll
        for (int j = 0; j < 4; j++) bfr[j] = *(const bf16x8*)(bF + j * 16 * BK);
#pragma unroll
        for (int i = 0; i < 4; i++)
#pragma unroll
            for (int j = 0; j < 4; j++)
                acc[i][j] = __builtin_amdgcn_mfma_f32_16x16x32_bf16(af[i], bfr[j], acc[i][j], 0, 0, 0);
        __syncthreads();
    }

    // epilogue: bias+gelu -> swizzled 128x128 bf16 C-buffer -> coalesced bf16x8 stores
    const float* __restrict__ b1e = b1 + (size_t)e * HID;
    float bj[4];
#pragma unroll
    for (int j = 0; j < 4; j++) bj[j] = b1e[n0 + col0 + j * 16 + lcol];
#pragma unroll
    for (int i = 0; i < 4; i++)
#pragma unroll
        for (int reg = 0; reg < 4; reg++) {
            int row = row0 + i * 16 + quad * 4 + reg;
#pragma unroll
            for (int j = 0; j < 4; j++) {
                int col = col0 + j * 16 + lcol;
                int slot = (col >> 3) ^ (row & 15);
                smem[row * 128 + slot * 8 + (col & 7)] =
                    (__bf16)gelu_tanh(acc[i][j][reg] + bj[j]);
            }
        }
    __syncthreads();
    {
        int row = tid >> 1, half = tid & 1;
        int pos = mstart + row;
        if (pos < ce) {
            __bf16* hp = h + (size_t)(offe + pos) * HID + n0 + half * 64;
#pragma unroll
            for (int j = 0; j < 8; j++) {
                int chunk = half * 8 + j;
                int slot = chunk ^ (row & 15);
                *(bf16x8*)(hp + j * 8) = *(const bf16x8*)&smem[row * 128 + slot * 8];
            }
        }
    }
}

// ---------------- GEMM2: out[tok] += w * (h @ W2e + b2), BK=32, split-K, XCD-grouped ----------------
// 1D grid 4096: L = xcd + 8*((n + 8*s) + 32*grp), key = grp*8+xcd = e*16+m.
// All 32 (n,s) blocks of one (e,m) share an XCD -> h-tile (1 MB) L2 reuse; W2 via L3.
__global__ __launch_bounds__(256, 4) void gemm2_kernel(
    const __bf16* __restrict__ h, const __bf16* __restrict__ W2T,
    const float* __restrict__ b2,
    const int* __restrict__ cnt,
    const int* __restrict__ tok, const float* __restrict__ wl,
    float* __restrict__ out) {
    const int L = blockIdx.x;
    const int xcd = L & 7;
    const int r1 = L >> 3;
    const int inner = r1 & 31;
    const int key = (r1 >> 5) * 8 + xcd;
    const int e = key >> 4;
    const int m = key & 15;
    const int n = inner & 7;
    const int split = inner >> 3;
    const int ce = cnt[e];
    const int mstart = m * BM;
    if (mstart >= ce) return;
    const int n0 = n * BN;
    const int ks = split * (HID / KSPLIT2);
    const int offe = expert_prefix(cnt, e);

    __shared__ __bf16 As[BM * BK];
    __shared__ __bf16 Bs[BN * BK];
    __shared__ int   toksh[BM];
    __shared__ float wsh[BM];

    const int tid = threadIdx.x;
    if (tid < BM) {
        int idx = mstart + tid;
        toksh[tid] = (idx < ce) ? tok[e * N_TOK + idx] : 0;
        wsh[tid]   = (idx < ce) ? wl[e * N_TOK + idx] : 0.f;
    }
    __syncthreads();

    const int lane = tid & 63;
    const int wid  = tid >> 6;
    const int row0 = (wid >> 1) * 64;
    const int col0 = (wid & 1) * 64;
    const int quad = lane >> 4;
    const int lcol = lane & 15;

    const int sub = lane >> 2;
    const int gk  = (((lane & 3) ^ (sub & 3)) << 3);
    const int ra0 = wid * 32 + sub;
    const int ra1 = ra0 + 16;

    int hr0 = offe + mstart + ra0; if (hr0 >= TOTPAIR) hr0 = TOTPAIR - 1;
    int hr1 = offe + mstart + ra1; if (hr1 >= TOTPAIR) hr1 = TOTPAIR - 1;

    const __bf16* __restrict__ W2e = W2T + (size_t)e * DIM * HID;
    const __bf16* pA0 = h + (size_t)hr0 * HID + ks + gk;
    const __bf16* pA1 = h + (size_t)hr1 * HID + ks + gk;
    const __bf16* pB0 = W2e + (size_t)(n0 + ra0) * HID + ks + gk;
    const __bf16* pB1 = W2e + (size_t)(n0 + ra1) * HID + ks + gk;
    __bf16* lA0 = &As[(wid * 2 + 0) * 512];
    __bf16* lA1 = &As[(wid * 2 + 1) * 512];
    __bf16* lB0 = &Bs[(wid * 2 + 0) * 512];
    __bf16* lB1 = &Bs[(wid * 2 + 1) * 512];

    const int swz = (quad ^ (lcol & 3)) << 3;
    const __bf16* aF = &As[(row0 + lcol) * BK + swz];
    const __bf16* bF = &Bs[(col0 + lcol) * BK + swz];

    f32x4 acc[4][4];
#pragma unroll
    for (int i = 0; i < 4; i++)
#pragma unroll
        for (int j = 0; j < 4; j++) acc[i][j] = (f32x4){0.f, 0.f, 0.f, 0.f};

    for (int k0 = 0; k0 < HID / KSPLIT2; k0 += BK) {
        stage16(pA0 + k0, lA0, lane);
        stage16(pA1 + k0, lA1, lane);
        stage16(pB0 + k0, lB0, lane);
        stage16(pB1 + k0, lB1, lane);
        __syncthreads();
        bf16x8 af[4], bfr[4];
#pragma unroll
        for (int i = 0; i < 4; i++) af[i]  = *(const bf16x8*)(aF + i * 16 * BK);
#pragma unroll
        for (int j = 0; j < 4; j++) bfr[j] = *(const bf16x8*)(bF + j * 16 * BK);
#pragma unroll
        for (int i = 0; i < 4; i++)
#pragma unroll
            for (int j = 0; j < 4; j++)
                acc[i][j] = __builtin_amdgcn_mfma_f32_16x16x32_bf16(af[i], bfr[j], acc[i][j], 0, 0, 0);
        __syncthreads();
    }

    const float* __restrict__ b2e = b2 + (size_t)e * DIM;
    const bool addBias = (split == 0);
#pragma unroll
    for (int i = 0; i < 4; i++) {
#pragma unroll
        for (int reg = 0; reg < 4; reg++) {
            int lrow = row0 + i * 16 + quad * 4 + reg;
            int pos = mstart + lrow;
            if (pos >= ce) continue;
            int tokm = toksh[lrow];
            float w = wsh[lrow];
#pragma unroll
            for (int j = 0; j < 4; j++) {
                int gcol = n0 + col0 + j * 16 + lcol;
                float v = acc[i][j][reg] + (addBias ? b2e[gcol] : 0.f);
                atomicAdd(&out[(size_t)tokm * DIM + gcol], w * v);
            }
        }
    }
}

// ---------------- fp32 fallback FFN ----------------
__global__ __launch_bounds__(256, 2) void ffn_fallback_kernel(
    const float* __restrict__ x,
    const float* __restrict__ W1, const float* __restrict__ b1,
    const float* __restrict__ W2, const float* __restrict__ b2,
    const int* __restrict__ cnt, const int* __restrict__ tok,
    const float* __restrict__ wl, float* __restrict__ out) {
    const int e = blockIdx.y;
    const int ce = cnt[e];
    const int start = blockIdx.x * 16;
    if (start >= ce) return;
    __shared__ float hs[16][128];
    __shared__ int toks[16];
    __shared__ float wgt[16];
    const int tid = threadIdx.x;
    if (tid < 16) {
        int idx = start + tid;
        if (idx < ce) { toks[tid] = tok[e * N_TOK + idx]; wgt[tid] = wl[e * N_TOK + idx]; }
        else          { toks[tid] = -1;                   wgt[tid] = 0.f; }
    }
    __syncthreads();
    const float* __restrict__ W1e = W1 + (size_t)e * DIM * HID;
    const float* __restrict__ W2e = W2 + (size_t)e * HID * DIM;
    const int am  = tid >> 4;
    const int aj0 = (tid & 15) * 8;
    const int at  = toks[am];
    const float* __restrict__ xrow = x + (size_t)(at < 0 ? 0 : at) * DIM;
    const int n0 = tid * 4;
    float acc[16][4];
#pragma unroll
    for (int m = 0; m < 16; m++)
#pragma unroll
        for (int i = 0; i < 4; i++) acc[m][i] = 0.f;
    for (int c = 0; c < HID; c += 128) {
        float ha[8];
#pragma unroll
        for (int r = 0; r < 8; r++) ha[r] = 0.f;
        const float* wp = W1e + c + aj0;
        for (int d = 0; d < DIM; d += 4) {
            float4 xv = *(const float4*)(xrow + d);
#pragma unroll
            for (int k = 0; k < 4; k++) {
                const float* wr = wp + (size_t)(d + k) * HID;
                float4 wa = *(const float4*)(wr);
                float4 wb = *(const float4*)(wr + 4);
                float xk = (k == 0) ? xv.x : (k == 1) ? xv.y : (k == 2) ? xv.z : xv.w;
                ha[0] = fmaf(xk, wa.x, ha[0]); ha[1] = fmaf(xk, wa.y, ha[1]);
                ha[2] = fmaf(xk, wa.z, ha[2]); ha[3] = fmaf(xk, wa.w, ha[3]);
                ha[4] = fmaf(xk, wb.x, ha[4]); ha[5] = fmaf(xk, wb.y, ha[5]);
                ha[6] = fmaf(xk, wb.z, ha[6]); ha[7] = fmaf(xk, wb.w, ha[7]);
            }
        }
        __syncthreads();
#pragma unroll
        for (int r = 0; r < 8; r++) {
            float v = ha[r] + b1[e * HID + c + aj0 + r];
            hs[am][aj0 + r] = gelu_tanh(v);
        }
        __syncthreads();
        for (int jj = 0; jj < 128; jj++) {
            float4 wv = *(const float4*)(W2e + (size_t)(c + jj) * DIM + n0);
#pragma unroll
            for (int m = 0; m < 16; m++) {
                float hv = hs[m][jj];
                acc[m][0] = fmaf(hv, wv.x, acc[m][0]); acc[m][1] = fmaf(hv, wv.y, acc[m][1]);
                acc[m][2] = fmaf(hv, wv.z, acc[m][2]); acc[m][3] = fmaf(hv, wv.w, acc[m][3]);
            }
        }
    }
    const float* bp = b2 + e * DIM + n0;
    float b0 = bp[0], b1v = bp[1], b2v = bp[2], b3 = bp[3];
#pragma unroll 1
    for (int m = 0; m < 16; m++) {
        int t = toks[m];
        if (t < 0) continue;
        float w = wgt[m];
        float* op = out + (size_t)t * DIM + n0;
        atomicAdd(op + 0, w * (acc[m][0] + b0));
        atomicAdd(op + 1, w * (acc[m][1] + b1v));
        atomicAdd(op + 2, w * (acc[m][2] + b2v));
        atomicAdd(op + 3, w * (acc[m][3] + b3));
    }
}

// ---------------- finalize ----------------
__global__ void finalize_kernel(const float* __restrict__ probs, const float* __restrict__ lsq,
                                const int* __restrict__ cnt, float* __restrict__ scal) {
    __shared__ float part[256][9];
    const int tid = threadIdx.x;
    float z = 0.f;
    float im[NEXP];
#pragma unroll
    for (int e = 0; e < NEXP; e++) im[e] = 0.f;
    for (int t = tid; t < N_TOK; t += 256) {
        z += lsq[t];
#pragma unroll
        for (int e = 0; e < NEXP; e++) im[e] += probs[t * NEXP + e];
    }
    part[tid][0] = z;
#pragma unroll
    for (int e = 0; e < NEXP; e++) part[tid][1 + e] = im[e];
    __syncthreads();
    if (tid == 0) {
        float zs = 0.f, ims[NEXP];
        for (int e = 0; e < NEXP; e++) ims[e] = 0.f;
        for (int i = 0; i < 256; i++) {
            zs += part[i][0];
            for (int e = 0; e < NEXP; e++) ims[e] += part[i][1 + e];
        }
        float nInv = 1.0f / (float)N_TOK;
        float aux = 0.f;
        for (int e = 0; e < NEXP; e++) aux += (ims[e] * nInv) * ((float)cnt[e] * nInv);
        scal[0] = zs * nInv;
        scal[1] = (float)NEXP * aux;
    }
}

extern "C" void kernel_launch(void* const* d_in, const int* in_sizes, int n_in,
                              void* d_out, int out_size, void* d_ws, size_t ws_size,
                              hipStream_t stream) {
    const float* x  = (const float*)d_in[0];
    const float* Wr = (const float*)d_in[1];
    const float* br = (const float*)d_in[2];
    const float* W1 = (const float*)d_in[3];
    const float* b1 = (const float*)d_in[4];
    const float* W2 = (const float*)d_in[5];
    const float* b2 = (const float*)d_in[6];
    float* out = (float*)d_out;

    char* base = (char*)d_ws;
    int*   cnt   = (int*)(base);
    int*   tokp  = (int*)(base + 64);
    float* wlp   = (float*)(base + 64 + 65536);
    float* probs = (float*)(base + 64 + 2 * 65536);
    float* lsq   = (float*)(base + 64 + 3 * 65536);
    const size_t SMALL_END = 64 + 3 * 65536 + 8192;
    __bf16* xb   = (__bf16*)(base + SMALL_END);
    __bf16* W1T  = (__bf16*)(base + SMALL_END + 4194304ull);
    __bf16* W2T  = (__bf16*)(base + SMALL_END + 4194304ull + 67108864ull);
    __bf16* hbuf = (__bf16*)(base + SMALL_END + 4194304ull + 2ull * 67108864ull);
    const size_t REQ = SMALL_END + 4194304ull + 2ull * 67108864ull + 33554432ull;

    hipMemsetAsync(base, 0, 64, stream);
    hipMemsetAsync(d_out, 0, (size_t)out_size * sizeof(float), stream);

    if (ws_size >= REQ) {
        prep_kernel<<<PREP_ROUTER + PREP_CONV + PREP_T1 + PREP_T2, 256, 0, stream>>>(
            x, Wr, br, probs, lsq, cnt, tokp, wlp, xb, W1, W1T, W2, W2T);
        gemm1_kernel<<<4096, 256, 0, stream>>>(xb, W1T, b1, cnt, tokp, hbuf);
        gemm2_kernel<<<4096, 256, 0, stream>>>(hbuf, W2T, b2, cnt, tokp, wlp, out);
    } else {
        router_kernel<<<N_TOK, 64, 0, stream>>>(x, Wr, br, probs, lsq, cnt, tokp, wlp);
        ffn_fallback_kernel<<<dim3(128, NEXP), 256, 0, stream>>>(
            x, W1, b1, W2, b2, cnt, tokp, wlp, out);
    }

    finalize_kernel<<<1, 256, 0, stream>>>(probs, lsq, cnt, out + (size_t)N_TOK * DIM);
}

// Round 6
// 540.141 us; speedup vs baseline: 1.4180x; 1.1734x over previous
//
#include <hip/hip_runtime.h>
#include <math.h>

#define N_TOK 2048
#define DIM   1024
#define NEXP  8
#define HID   4096
#define TOTPAIR (2 * N_TOK)

#define BM 128
#define BN 128
#define BK 32
#define KSPLIT2 4

typedef __bf16 bf16x8 __attribute__((ext_vector_type(8)));
typedef __bf16 bf16x4 __attribute__((ext_vector_type(4)));
typedef float  f32x4  __attribute__((ext_vector_type(4)));

__device__ __forceinline__ float gelu_tanh(float v) {
    float a = 0.7978845608028654f * (v + 0.044715f * v * v * v);
    a = fminf(fmaxf(a, -15.f), 15.f);
    float t = __expf(-2.f * a);
    return 0.5f * v * (1.f + (1.f - t) / (1.f + t));
}

// Stage 16B/lane: global -> LDS (wave-uniform base; HW scatters lane i -> base+16i).
__device__ __forceinline__ void stage16(const __bf16* g, __bf16* lds_base, int lane) {
#if defined(__has_builtin) && __has_builtin(__builtin_amdgcn_global_load_lds)
    __builtin_amdgcn_global_load_lds((const __attribute__((address_space(1))) void*)g,
                                     (__attribute__((address_space(3))) void*)lds_base,
                                     16, 0, 0);
#else
    *(bf16x8*)((char*)lds_base + (size_t)lane * 16) = *(const bf16x8*)g;
#endif
}

__device__ __forceinline__ int expert_prefix(const int* cnt, int e) {
    int s = 0;
    for (int i = 0; i < NEXP; i++) s += (i < e) ? cnt[i] : 0;
    return s;
}

// ---------------- router body (one wave per token) ----------------
__device__ __forceinline__ void router_body(
    int t, int lane,
    const float* __restrict__ x, const float* __restrict__ Wr, const float* __restrict__ br,
    float* __restrict__ probs, float* __restrict__ lsq,
    int* __restrict__ cnt, int* __restrict__ tok, float* __restrict__ wl) {
    const float* xr = x + (size_t)t * DIM;
    float acc[NEXP];
#pragma unroll
    for (int e = 0; e < NEXP; e++) acc[e] = 0.f;
    for (int d = lane; d < DIM; d += 64) {
        float xv = xr[d];
        const float* wr = Wr + (size_t)d * NEXP;
#pragma unroll
        for (int e = 0; e < NEXP; e++) acc[e] = fmaf(xv, wr[e], acc[e]);
    }
#pragma unroll
    for (int off = 32; off >= 1; off >>= 1) {
#pragma unroll
        for (int e = 0; e < NEXP; e++) acc[e] += __shfl_xor(acc[e], off, 64);
    }
    if (lane == 0) {
        float lg[NEXP], mx = -1e30f;
#pragma unroll
        for (int e = 0; e < NEXP; e++) { lg[e] = acc[e] + br[e]; mx = fmaxf(mx, lg[e]); }
        float se = 0.f, p[NEXP];
#pragma unroll
        for (int e = 0; e < NEXP; e++) { p[e] = expf(lg[e] - mx); se += p[e]; }
        float inv = 1.f / se;
        float lse = mx + logf(se);
        lsq[t] = lse * lse;
#pragma unroll
        for (int e = 0; e < NEXP; e++) probs[t * NEXP + e] = p[e] * inv;
        int i0 = 0;
#pragma unroll
        for (int e = 1; e < NEXP; e++) if (p[e] > p[i0]) i0 = e;
        int i1 = (i0 == 0) ? 1 : 0;
#pragma unroll
        for (int e = 0; e < NEXP; e++) if (e != i0 && p[e] > p[i1]) i1 = e;
        float p0 = p[i0] * inv, p1 = p[i1] * inv;
        float rn = 1.f / (p0 + p1 + 1e-12f);
        int pos0 = atomicAdd(&cnt[i0], 1);
        tok[i0 * N_TOK + pos0] = t;
        wl[i0 * N_TOK + pos0] = p0 * rn;
        int pos1 = atomicAdd(&cnt[i1], 1);
        tok[i1 * N_TOK + pos1] = t;
        wl[i1 * N_TOK + pos1] = p1 * rn;
    }
}

// ---------------- standalone router (fallback path) ----------------
__global__ void router_kernel(const float* __restrict__ x, const float* __restrict__ Wr,
                              const float* __restrict__ br,
                              float* __restrict__ probs, float* __restrict__ lsq,
                              int* __restrict__ cnt, int* __restrict__ tok,
                              float* __restrict__ wl) {
    router_body(blockIdx.x, threadIdx.x, x, Wr, br, probs, lsq, cnt, tok, wl);
}

// ---------------- small fused prep: router (512 blocks) + x->bf16 (2048 blocks) ----------------
__global__ __launch_bounds__(256) void prep_kernel(
    const float* __restrict__ x, const float* __restrict__ Wr, const float* __restrict__ br,
    float* __restrict__ probs, float* __restrict__ lsq,
    int* __restrict__ cnt, int* __restrict__ tok, float* __restrict__ wl,
    __bf16* __restrict__ xb) {
    const int b = blockIdx.x;
    const int tid = threadIdx.x;
    if (b < 512) {
        int t = b * 4 + (tid >> 6);
        router_body(t, tid & 63, x, Wr, br, probs, lsq, cnt, tok, wl);
        return;
    }
    int idx = (b - 512) * 256 + tid;
    float4 v = ((const float4*)x)[idx];
    bf16x4 o;
    o.x = (__bf16)v.x; o.y = (__bf16)v.y; o.z = (__bf16)v.z; o.w = (__bf16)v.w;
    ((bf16x4*)xb)[idx] = o;
}

// ---------------- GEMM1: h = gelu(gather(x) @ W1e + b1), fp32 W1 consumed directly ----------------
// A: bf16 xb rows via global_load_lds, layout [row][32k], source-chunk swizzle.
// B: fp32 W1 [k][n] rows -> cvt -> transposed ds_write_b64 into chunked Bs[slot][128n][8k],
//    slot = kchunk ^ (n&3). Fragment reads are single b128 for both A and B.
__global__ __launch_bounds__(256, 4) void gemm1_kernel(
    const __bf16* __restrict__ xb, const float* __restrict__ W1,
    const float* __restrict__ b1,
    const int* __restrict__ cnt,
    const int* __restrict__ tok, __bf16* __restrict__ h) {
    const int e = blockIdx.z;
    const int ce = cnt[e];
    const int mstart = blockIdx.y * BM;
    if (mstart >= ce) return;
    const int n0 = blockIdx.x * BN;
    const int offe = expert_prefix(cnt, e);

    __shared__ __bf16 smem[BM * 128];   // 32 KB: As [0,4096), Bs [4096,8192); full = C-buffer
    __shared__ int toksh[BM];
    __bf16* As = smem;
    __bf16* Bs = smem + 4096;

    const int tid = threadIdx.x;
    if (tid < BM) {
        int idx = mstart + tid;
        toksh[tid] = (idx < ce) ? tok[e * N_TOK + idx] : 0;
    }
    __syncthreads();

    const int lane = tid & 63;
    const int wid  = tid >> 6;
    const int row0 = (wid >> 1) * 64;
    const int col0 = (wid & 1) * 64;
    const int quad = lane >> 4;
    const int lcol = lane & 15;

    // A staging (round-3 scheme): wave stages 32 rows, source-chunk swizzled
    const int sub = lane >> 2;
    const int gk  = (((lane & 3) ^ (sub & 3)) << 3);
    const int ra0 = wid * 32 + sub;
    const int ra1 = ra0 + 16;
    const __bf16* pA0 = xb + (size_t)toksh[ra0] * DIM + gk;
    const __bf16* pA1 = xb + (size_t)toksh[ra1] * DIM + gk;
    __bf16* lA0 = &As[(wid * 2 + 0) * 512];
    __bf16* lA1 = &As[(wid * 2 + 1) * 512];

    // B staging: wave covers 64 n x 16 k
    const int khalf = (wid >> 1) * 16;
    const int nl    = (wid & 1) * 64 + lane;
    const float* __restrict__ W1e = W1 + (size_t)e * DIM * HID;
    const float* wsrc = W1e + (size_t)khalf * HID + n0 + nl;

    const int aswz = (quad ^ (lcol & 3)) << 3;
    const __bf16* aF = &As[(row0 + lcol) * BK + aswz];

    f32x4 acc[4][4];
#pragma unroll
    for (int i = 0; i < 4; i++)
#pragma unroll
        for (int j = 0; j < 4; j++) acc[i][j] = (f32x4){0.f, 0.f, 0.f, 0.f};

    for (int k0 = 0; k0 < DIM; k0 += BK) {
        // issue B loads (fp32, coalesced 256B/instr)
        float v[16];
        const float* ws = wsrc + (size_t)k0 * HID;
#pragma unroll
        for (int j = 0; j < 16; j++) v[j] = ws[(size_t)j * HID];
        // async A staging
        stage16(pA0 + k0, lA0, lane);
        stage16(pA1 + k0, lA1, lane);
        // cvt + transposed b64 writes into chunked Bs
#pragma unroll
        for (int q = 0; q < 4; q++) {
            bf16x4 pk;
            pk.x = (__bf16)v[q * 4 + 0]; pk.y = (__bf16)v[q * 4 + 1];
            pk.z = (__bf16)v[q * 4 + 2]; pk.w = (__bf16)v[q * 4 + 3];
            int c = (wid >> 1) * 2 + (q >> 1);
            int slot = c ^ (nl & 3);
            *(bf16x4*)&Bs[slot * 1024 + nl * 8 + (q & 1) * 4] = pk;
        }
        __syncthreads();
        bf16x8 af[4], bfr[4];
#pragma unroll
        for (int i = 0; i < 4; i++) af[i]  = *(const bf16x8*)(aF + i * 16 * BK);
#pragma unroll
        for (int j = 0; j < 4; j++)
            bfr[j] = *(const bf16x8*)&Bs[((quad ^ (lcol & 3)) * 1024) + (col0 + j * 16 + lcol) * 8];
#pragma unroll
        for (int i = 0; i < 4; i++)
#pragma unroll
            for (int j = 0; j < 4; j++)
                acc[i][j] = __builtin_amdgcn_mfma_f32_16x16x32_bf16(af[i], bfr[j], acc[i][j], 0, 0, 0);
        __syncthreads();
    }

    // epilogue: bias+gelu -> swizzled 128x128 bf16 C-buffer -> coalesced bf16x8 stores
    const float* __restrict__ b1e = b1 + (size_t)e * HID;
    float bj[4];
#pragma unroll
    for (int j = 0; j < 4; j++) bj[j] = b1e[n0 + col0 + j * 16 + lcol];
#pragma unroll
    for (int i = 0; i < 4; i++)
#pragma unroll
        for (int reg = 0; reg < 4; reg++) {
            int row = row0 + i * 16 + quad * 4 + reg;
#pragma unroll
            for (int j = 0; j < 4; j++) {
                int col = col0 + j * 16 + lcol;
                int slot = (col >> 3) ^ (row & 15);
                smem[row * 128 + slot * 8 + (col & 7)] =
                    (__bf16)gelu_tanh(acc[i][j][reg] + bj[j]);
            }
        }
    __syncthreads();
    {
        int row = tid >> 1, half = tid & 1;
        int pos = mstart + row;
        if (pos < ce) {
            __bf16* hp = h + (size_t)(offe + pos) * HID + n0 + half * 64;
#pragma unroll
            for (int j = 0; j < 8; j++) {
                int chunk = half * 8 + j;
                int slot = chunk ^ (row & 15);
                *(bf16x8*)(hp + j * 8) = *(const bf16x8*)&smem[row * 128 + slot * 8];
            }
        }
    }
}

// ---------------- GEMM2: out[tok] += w * (h @ W2e + b2), split-K, fp32 W2 direct ----------------
__global__ __launch_bounds__(256, 4) void gemm2_kernel(
    const __bf16* __restrict__ h, const float* __restrict__ W2,
    const float* __restrict__ b2,
    const int* __restrict__ cnt,
    const int* __restrict__ tok, const float* __restrict__ wl,
    float* __restrict__ out) {
    const int e = blockIdx.z >> 2;
    const int split = blockIdx.z & 3;
    const int ce = cnt[e];
    const int mstart = blockIdx.y * BM;
    if (mstart >= ce) return;
    const int n0 = blockIdx.x * BN;
    const int ks = split * (HID / KSPLIT2);
    const int offe = expert_prefix(cnt, e);

    __shared__ __bf16 As[BM * BK];
    __shared__ __bf16 Bs[4 * 128 * 8];
    __shared__ int   toksh[BM];
    __shared__ float wsh[BM];

    const int tid = threadIdx.x;
    if (tid < BM) {
        int idx = mstart + tid;
        toksh[tid] = (idx < ce) ? tok[e * N_TOK + idx] : 0;
        wsh[tid]   = (idx < ce) ? wl[e * N_TOK + idx] : 0.f;
    }
    __syncthreads();

    const int lane = tid & 63;
    const int wid  = tid >> 6;
    const int row0 = (wid >> 1) * 64;
    const int col0 = (wid & 1) * 64;
    const int quad = lane >> 4;
    const int lcol = lane & 15;

    const int sub = lane >> 2;
    const int gk  = (((lane & 3) ^ (sub & 3)) << 3);
    const int ra0 = wid * 32 + sub;
    const int ra1 = ra0 + 16;
    int hr0 = offe + mstart + ra0; if (hr0 >= TOTPAIR) hr0 = TOTPAIR - 1;
    int hr1 = offe + mstart + ra1; if (hr1 >= TOTPAIR) hr1 = TOTPAIR - 1;
    const __bf16* pA0 = h + (size_t)hr0 * HID + ks + gk;
    const __bf16* pA1 = h + (size_t)hr1 * HID + ks + gk;
    __bf16* lA0 = &As[(wid * 2 + 0) * 512];
    __bf16* lA1 = &As[(wid * 2 + 1) * 512];

    const int khalf = (wid >> 1) * 16;
    const int nl    = (wid & 1) * 64 + lane;
    const float* __restrict__ W2e = W2 + (size_t)e * HID * DIM;
    const float* wsrc = W2e + (size_t)(ks + khalf) * DIM + n0 + nl;

    const int aswz = (quad ^ (lcol & 3)) << 3;
    const __bf16* aF = &As[(row0 + lcol) * BK + aswz];

    f32x4 acc[4][4];
#pragma unroll
    for (int i = 0; i < 4; i++)
#pragma unroll
        for (int j = 0; j < 4; j++) acc[i][j] = (f32x4){0.f, 0.f, 0.f, 0.f};

    for (int k0 = 0; k0 < HID / KSPLIT2; k0 += BK) {
        float v[16];
        const float* ws = wsrc + (size_t)k0 * DIM;
#pragma unroll
        for (int j = 0; j < 16; j++) v[j] = ws[(size_t)j * DIM];
        stage16(pA0 + k0, lA0, lane);
        stage16(pA1 + k0, lA1, lane);
#pragma unroll
        for (int q = 0; q < 4; q++) {
            bf16x4 pk;
            pk.x = (__bf16)v[q * 4 + 0]; pk.y = (__bf16)v[q * 4 + 1];
            pk.z = (__bf16)v[q * 4 + 2]; pk.w = (__bf16)v[q * 4 + 3];
            int c = (wid >> 1) * 2 + (q >> 1);
            int slot = c ^ (nl & 3);
            *(bf16x4*)&Bs[slot * 1024 + nl * 8 + (q & 1) * 4] = pk;
        }
        __syncthreads();
        bf16x8 af[4], bfr[4];
#pragma unroll
        for (int i = 0; i < 4; i++) af[i]  = *(const bf16x8*)(aF + i * 16 * BK);
#pragma unroll
        for (int j = 0; j < 4; j++)
            bfr[j] = *(const bf16x8*)&Bs[((quad ^ (lcol & 3)) * 1024) + (col0 + j * 16 + lcol) * 8];
#pragma unroll
        for (int i = 0; i < 4; i++)
#pragma unroll
            for (int j = 0; j < 4; j++)
                acc[i][j] = __builtin_amdgcn_mfma_f32_16x16x32_bf16(af[i], bfr[j], acc[i][j], 0, 0, 0);
        __syncthreads();
    }

    const float* __restrict__ b2e = b2 + (size_t)e * DIM;
    const bool addBias = (split == 0);
#pragma unroll
    for (int i = 0; i < 4; i++) {
#pragma unroll
        for (int reg = 0; reg < 4; reg++) {
            int lrow = row0 + i * 16 + quad * 4 + reg;
            int pos = mstart + lrow;
            if (pos >= ce) continue;
            int tokm = toksh[lrow];
            float w = wsh[lrow];
#pragma unroll
            for (int j = 0; j < 4; j++) {
                int gcol = n0 + col0 + j * 16 + lcol;
                float vv = acc[i][j][reg] + (addBias ? b2e[gcol] : 0.f);
                atomicAdd(&out[(size_t)tokm * DIM + gcol], w * vv);
            }
        }
    }
}

// ---------------- fp32 fallback FFN ----------------
__global__ __launch_bounds__(256, 2) void ffn_fallback_kernel(
    const float* __restrict__ x,
    const float* __restrict__ W1, const float* __restrict__ b1,
    const float* __restrict__ W2, const float* __restrict__ b2,
    const int* __restrict__ cnt, const int* __restrict__ tok,
    const float* __restrict__ wl, float* __restrict__ out) {
    const int e = blockIdx.y;
    const int ce = cnt[e];
    const int start = blockIdx.x * 16;
    if (start >= ce) return;
    __shared__ float hs[16][128];
    __shared__ int toks[16];
    __shared__ float wgt[16];
    const int tid = threadIdx.x;
    if (tid < 16) {
        int idx = start + tid;
        if (idx < ce) { toks[tid] = tok[e * N_TOK + idx]; wgt[tid] = wl[e * N_TOK + idx]; }
        else          { toks[tid] = -1;                   wgt[tid] = 0.f; }
    }
    __syncthreads();
    const float* __restrict__ W1e = W1 + (size_t)e * DIM * HID;
    const float* __restrict__ W2e = W2 + (size_t)e * HID * DIM;
    const int am  = tid >> 4;
    const int aj0 = (tid & 15) * 8;
    const int at  = toks[am];
    const float* __restrict__ xrow = x + (size_t)(at < 0 ? 0 : at) * DIM;
    const int n0 = tid * 4;
    float acc[16][4];
#pragma unroll
    for (int m = 0; m < 16; m++)
#pragma unroll
        for (int i = 0; i < 4; i++) acc[m][i] = 0.f;
    for (int c = 0; c < HID; c += 128) {
        float ha[8];
#pragma unroll
        for (int r = 0; r < 8; r++) ha[r] = 0.f;
        const float* wp = W1e + c + aj0;
        for (int d = 0; d < DIM; d += 4) {
            float4 xv = *(const float4*)(xrow + d);
#pragma unroll
            for (int k = 0; k < 4; k++) {
                const float* wr = wp + (size_t)(d + k) * HID;
                float4 wa = *(const float4*)(wr);
                float4 wb = *(const float4*)(wr + 4);
                float xk = (k == 0) ? xv.x : (k == 1) ? xv.y : (k == 2) ? xv.z : xv.w;
                ha[0] = fmaf(xk, wa.x, ha[0]); ha[1] = fmaf(xk, wa.y, ha[1]);
                ha[2] = fmaf(xk, wa.z, ha[2]); ha[3] = fmaf(xk, wa.w, ha[3]);
                ha[4] = fmaf(xk, wb.x, ha[4]); ha[5] = fmaf(xk, wb.y, ha[5]);
                ha[6] = fmaf(xk, wb.z, ha[6]); ha[7] = fmaf(xk, wb.w, ha[7]);
            }
        }
        __syncthreads();
#pragma unroll
        for (int r = 0; r < 8; r++) {
            float v = ha[r] + b1[e * HID + c + aj0 + r];
            hs[am][aj0 + r] = gelu_tanh(v);
        }
        __syncthreads();
        for (int jj = 0; jj < 128; jj++) {
            float4 wv = *(const float4*)(W2e + (size_t)(c + jj) * DIM + n0);
#pragma unroll
            for (int m = 0; m < 16; m++) {
                float hv = hs[m][jj];
                acc[m][0] = fmaf(hv, wv.x, acc[m][0]); acc[m][1] = fmaf(hv, wv.y, acc[m][1]);
                acc[m][2] = fmaf(hv, wv.z, acc[m][2]); acc[m][3] = fmaf(hv, wv.w, acc[m][3]);
            }
        }
    }
    const float* bp = b2 + e * DIM + n0;
    float b0 = bp[0], b1v = bp[1], b2v = bp[2], b3 = bp[3];
#pragma unroll 1
    for (int m = 0; m < 16; m++) {
        int t = toks[m];
        if (t < 0) continue;
        float w = wgt[m];
        float* op = out + (size_t)t * DIM + n0;
        atomicAdd(op + 0, w * (acc[m][0] + b0));
        atomicAdd(op + 1, w * (acc[m][1] + b1v));
        atomicAdd(op + 2, w * (acc[m][2] + b2v));
        atomicAdd(op + 3, w * (acc[m][3] + b3));
    }
}

// ---------------- finalize ----------------
__global__ void finalize_kernel(const float* __restrict__ probs, const float* __restrict__ lsq,
                                const int* __restrict__ cnt, float* __restrict__ scal) {
    __shared__ float part[256][9];
    const int tid = threadIdx.x;
    float z = 0.f;
    float im[NEXP];
#pragma unroll
    for (int e = 0; e < NEXP; e++) im[e] = 0.f;
    for (int t = tid; t < N_TOK; t += 256) {
        z += lsq[t];
#pragma unroll
        for (int e = 0; e < NEXP; e++) im[e] += probs[t * NEXP + e];
    }
    part[tid][0] = z;
#pragma unroll
    for (int e = 0; e < NEXP; e++) part[tid][1 + e] = im[e];
    __syncthreads();
    if (tid == 0) {
        float zs = 0.f, ims[NEXP];
        for (int e = 0; e < NEXP; e++) ims[e] = 0.f;
        for (int i = 0; i < 256; i++) {
            zs += part[i][0];
            for (int e = 0; e < NEXP; e++) ims[e] += part[i][1 + e];
        }
        float nInv = 1.0f / (float)N_TOK;
        float aux = 0.f;
        for (int e = 0; e < NEXP; e++) aux += (ims[e] * nInv) * ((float)cnt[e] * nInv);
        scal[0] = zs * nInv;
        scal[1] = (float)NEXP * aux;
    }
}

extern "C" void kernel_launch(void* const* d_in, const int* in_sizes, int n_in,
                              void* d_out, int out_size, void* d_ws, size_t ws_size,
                              hipStream_t stream) {
    const float* x  = (const float*)d_in[0];
    const float* Wr = (const float*)d_in[1];
    const float* br = (const float*)d_in[2];
    const float* W1 = (const float*)d_in[3];
    const float* b1 = (const float*)d_in[4];
    const float* W2 = (const float*)d_in[5];
    const float* b2 = (const float*)d_in[6];
    float* out = (float*)d_out;

    char* base = (char*)d_ws;
    int*   cnt   = (int*)(base);
    int*   tokp  = (int*)(base + 64);
    float* wlp   = (float*)(base + 64 + 65536);
    float* probs = (float*)(base + 64 + 2 * 65536);
    float* lsq   = (float*)(base + 64 + 3 * 65536);
    const size_t SMALL_END = 64 + 3 * 65536 + 8192;   // 204,864
    __bf16* xb   = (__bf16*)(base + SMALL_END);                    // 4 MB
    __bf16* hbuf = (__bf16*)(base + SMALL_END + 4194304ull);       // 32 MB
    const size_t REQ = SMALL_END + 4194304ull + 33554432ull;       // ~38 MB

    hipMemsetAsync(base, 0, 64, stream);
    hipMemsetAsync(d_out, 0, (size_t)out_size * sizeof(float), stream);

    if (ws_size >= REQ) {
        prep_kernel<<<512 + 2048, 256, 0, stream>>>(
            x, Wr, br, probs, lsq, cnt, tokp, wlp, xb);
        gemm1_kernel<<<dim3(HID / BN, N_TOK / BM, NEXP), 256, 0, stream>>>(
            xb, W1, b1, cnt, tokp, hbuf);
        gemm2_kernel<<<dim3(DIM / BN, N_TOK / BM, NEXP * KSPLIT2), 256, 0, stream>>>(
            hbuf, W2, b2, cnt, tokp, wlp, out);
    } else {
        router_kernel<<<N_TOK, 64, 0, stream>>>(x, Wr, br, probs, lsq, cnt, tokp, wlp);
        ffn_fallback_kernel<<<dim3(128, NEXP), 256, 0, stream>>>(
            x, W1, b1, W2, b2, cnt, tokp, wlp, out);
    }

    finalize_kernel<<<1, 256, 0, stream>>>(probs, lsq, cnt, out + (size_t)N_TOK * DIM);
}